// Round 4
// baseline (307.921 us; speedup 1.0000x reference)
//
#include <hip/hip_runtime.h>

// Head_13: fused single-head causal attention, B=1024 T=128 C=384 HS=64, fp32 I/O.
// One block (8 waves, 512 thr) per batch. bf16 MFMA 32x32x16. __launch_bounds__(512,4)
// -> 16 waves/CU (2 blocks), 2x the old 4-wave/256-reg layout's occupancy.
// Phase 1 (QKV proj): reg-staged depth-2 pipeline (32B/thread/chunk), bf16 chunk buffer
// in LDS (pitch 80B), raw s_barrier + lgkmcnt(0) only (vmcnt never drained in-loop).
// Each wave: 1 M-tile x 3 N-tiles (acc[3] = 48 regs). W fragment-major bf16 (L2).
// Phase 2: col-tiles split across wave pairs (cg = ct&1); cross-wave rowsum and
// O-partial reduction via small LDS buffers. Max 2 S-tiles per wave (was 4).

typedef __attribute__((ext_vector_type(8)))  short  short8;   // 8 bf16 = 4 VGPR
typedef __attribute__((ext_vector_type(16))) float  floatx16; // MFMA 32x32 acc
typedef __attribute__((ext_vector_type(4)))  float  float4v;

#define T_DIM   128
#define C_DIM   384
#define HS      64
#define NCHUNK  12            // 384/32
#define SLAB    1536          // shorts per (c,ks,half) slab = 192 n * 8 k

#define QK_PITCH 68           // 64+4 bf16 -> 136 B row (8B-aligned, 2-way banks = free)
#define V_PITCH  132          // 128+4 bf16 -> 264 B
#define P_PITCH  132
#define Q_OFF 0
#define K_OFF 17408           // 128*136
#define V_OFF 34816
#define RS_OFF 51712          // rowsum exchange: [rt][cg][row32] f32 = 1024 B
#define LDS_BYTES 52736
#define P_OFF 0               // P [128][132]*2 = 33792 overlays q + head of k (dead in 2b)
#define OX_OFF 0              // O-partial exchange [rt][32][64] f32 = 32768, P dead then
#define XS_OFF 0              // x bf16 staging: 2 x 10240 B overlays q (dead until epilogue)
#define XS_BUF 10240          // one chunk: 128 rows x 80 B pitch (64 B bf16 + 16 pad)
#define XP    80              // chunk-buffer row pitch in bytes

#define MFMA(a,b,c) __builtin_amdgcn_mfma_f32_32x32x16_bf16((a),(b),(c),0,0,0)

__device__ inline unsigned short f2bf(float f){ // fp32 -> bf16 RTNE
    unsigned u = __builtin_bit_cast(unsigned, f);
    u += 0x7FFFu + ((u >> 16) & 1u);
    return (unsigned short)(u >> 16);
}

__device__ inline short8 ld_b64x2(const char* p){ // 16B fragment via two 8B LDS reads
    union { unsigned long long u[2]; short8 s; } r;
    r.u[0] = *(const unsigned long long*)(p);
    r.u[1] = *(const unsigned long long*)(p + 8);
    return r.s;
}

// W[q|k|v] fp32 [384][64] -> wt bf16 fragment-major: [c][ks][half][n=192][j=8]
// short index = ((c*2+ks)*2+half)*1536 + n*8 + j ; k_global = c*32+ks*16+half*8+j
__global__ void prep_wt(const float* __restrict__ Wq, const float* __restrict__ Wk,
                        const float* __restrict__ Wv, unsigned short* __restrict__ wt){
    int idx = blockIdx.x * 256 + threadIdx.x;
    if (idx >= 48 * SLAB) return;
    int slab = idx / SLAB;
    int rem  = idx - slab * SLAB;
    int n = rem >> 3, j = rem & 7;
    int half = slab & 1, ks = (slab >> 1) & 1, c = slab >> 2;
    int kg = c*32 + ks*16 + half*8 + j;
    const float* W = (n < 64) ? Wq : (n < 128) ? Wk : Wv;
    wt[idx] = f2bf(W[kg * HS + (n & 63)]);
}

__launch_bounds__(512, 4)
__global__ void attn_kernel(const float* __restrict__ x,
                            const unsigned short* __restrict__ wtg,
                            float* __restrict__ out){
    __shared__ __align__(16) char smem[LDS_BYTES];
    const int tid  = threadIdx.x;
    const int lane = tid & 63;
    const int wave = tid >> 6;            // 0..7
    const int l31  = lane & 31;
    const int half = lane >> 5;
    const int koff = half * 8;            // MFMA k-split: lanes 32-63 hold k+8..k+15
    const int b    = blockIdx.x;
    const float* xb = x + (size_t)b * (T_DIM * C_DIM);

    // ---------------- phase 1: [q|k|v] = x[b] @ Wt ------------------------------
    const int mblk = wave & 3;            // rows 32*mblk .. +31
    const int ngrp = wave >> 2;           // wt cols 96*ngrp .. +95 (3 N-tiles)
    const short8* wf = (const short8*)wtg;
    const int nbase = 96 * ngrp + l31;

    // staging role: thread -> (row, 32B part) of the 128x32 fp32 chunk
    const int srow  = tid >> 2;           // 0..127
    const int spart = tid & 3;            // floats [8*spart, 8*spart+8)
    char* const bw0 = smem + XS_OFF + srow * XP + spart * 16;     // bf16 dest (16 B)
    const float* const xs0 = xb + srow * C_DIM + spart * 8;

    float4v ldreg[2][2];                  // fp32 in-flight strips, 2 chunks deep
    auto xload = [&](int c, int s){       // 2 coalesced dwordx4, compiler-counted vmcnt
        const float4v* g = (const float4v*)(xs0 + c * 32);
        ldreg[s][0] = g[0]; ldreg[s][1] = g[1];
    };
    auto cw = [&](int s, int sb){         // convert once -> bf16 chunk buffer (16 B write)
        short8 o;
        #pragma unroll
        for (int j = 0; j < 8; ++j)
            o[j] = (short)f2bf(ldreg[s][j >> 2][j & 3]);
        *(short8*)(bw0 + sb * XS_BUF) = o;
    };

    floatx16 acc[3] = {};                 // [nbl]
    short8 bfr[2][3];                     // W fragments (single-buffered)
    auto wload = [&](int c){
        #pragma unroll
        for (int ks = 0; ks < 2; ++ks)
            #pragma unroll
            for (int nbl = 0; nbl < 3; ++nbl)
                bfr[ks][nbl] = wf[((c*2 + ks)*2 + half)*192 + nbase + 32*nbl];
    };

    // prologue: chunks 0,1 to regs; W(0); chunk 0 -> LDS
    xload(0, 0);
    xload(1, 1);
    wload(0);
    cw(0, 0);                             // waits only on ldreg[0]'s loads
    asm volatile("s_waitcnt lgkmcnt(0)" ::: "memory");
    __builtin_amdgcn_s_barrier();
    asm volatile("" ::: "memory");

    #pragma unroll
    for (int c = 0; c < NCHUNK; ++c){
        if (c + 2 < NCHUNK) xload(c + 2, c & 1);     // refill freed slot
        if (c + 1 < NCHUNK) cw((c+1)&1, (c+1)&1);    // convert+write next chunk

        // A fragments: direct bf16 ds_read_b128 from buf[c&1]
        const char* sbuf = smem + XS_OFF + (c & 1) * XS_BUF;
        const int R = 32*mblk + l31;
        short8 afr0 = *(const short8*)(sbuf + R * XP + 0*32 + half*16);
        short8 afr1 = *(const short8*)(sbuf + R * XP + 1*32 + half*16);
        #pragma unroll
        for (int nbl = 0; nbl < 3; ++nbl)
            acc[nbl] = MFMA(afr0, bfr[0][nbl], acc[nbl]);
        #pragma unroll
        for (int nbl = 0; nbl < 3; ++nbl)
            acc[nbl] = MFMA(afr1, bfr[1][nbl], acc[nbl]);

        if (c + 1 < NCHUNK){
            wload(c + 1);                 // W for next chunk; latency hidden by barrier+cw
            asm volatile("s_waitcnt lgkmcnt(0)" ::: "memory");
            __builtin_amdgcn_s_barrier();
            asm volatile("" ::: "memory");
        }
    }
    __syncthreads();   // full drain: chunk-buffer reads done before epilogue overwrites

    // write q,k (row-major, softmax scale*log2e folded into q) and v (h-major) to LDS
    const float QSCALE = 0.125f * 1.44269504088896f;
    #pragma unroll
    for (int nbl = 0; nbl < 3; ++nbl){
        floatx16 A = acc[nbl];
        int nb = 3*ngrp + nbl;            // 0..5: q q k k v v
        int mb = mblk;
        if (nb < 4){
            int base  = (nb < 2) ? Q_OFF : K_OFF;
            int col   = 32 * (nb & 1) + l31;
            float sc  = (nb < 2) ? QSCALE : 1.0f;
            char* bp  = smem + base + col * 2;
            #pragma unroll
            for (int r = 0; r < 16; ++r){
                int t = 32*mb + (r&3) + 8*(r>>2) + 4*half;   // verified C/D row map
                *(unsigned short*)(bp + t * (QK_PITCH*2)) = f2bf(A[r] * sc);
            }
        } else {
            int h = 32*(nb-4) + l31;
            char* bp = smem + V_OFF + h * (V_PITCH*2);
            #pragma unroll
            for (int g = 0; g < 4; ++g){
                int t0 = 32*mb + 8*g + 4*half;   // regs 4g..4g+3 = 4 consecutive rows
                union { unsigned short s[4]; unsigned long long u; } pk;
                pk.s[0]=f2bf(A[4*g+0]); pk.s[1]=f2bf(A[4*g+1]);
                pk.s[2]=f2bf(A[4*g+2]); pk.s[3]=f2bf(A[4*g+3]);
                *(unsigned long long*)(bp + t0*2) = pk.u;
            }
        }
    }
    __syncthreads();

    // ---------------- phase 2a: S = q k^T (causal), P = exp2(S) ----------------
    // row-tile rt = wave&3 (rows 32rt..+31); col-group cg = wave>>2 owns ct with
    // ct&1 == cg, ct <= rt. Max 2 S-tiles/wave. accS[i] <-> ct = cg + 2i.
    const int rt = wave & 3;
    const int cg = wave >> 2;
    floatx16 accS[2] = {};
    #pragma unroll
    for (int ks = 0; ks < 4; ++ks){
        short8 aq = ld_b64x2(smem + Q_OFF + (32*rt + l31)*(QK_PITCH*2) + (ks*16 + koff)*2);
        #pragma unroll
        for (int i = 0; i < 2; ++i){
            int ct = cg + 2*i;
            if (ct <= rt){                // wave-uniform predicate
                short8 bk = ld_b64x2(smem + K_OFF + (32*ct + l31)*(QK_PITCH*2) + (ks*16 + koff)*2);
                accS[i] = MFMA(aq, bk, accS[i]);
            }
        }
    }
    // |logit| <~ 8 -> exp2 safe in fp32 without max-subtraction
    #pragma unroll
    for (int i = 0; i < 2; ++i){
        int ct = cg + 2*i;
        if (ct <= rt){
            #pragma unroll
            for (int r = 0; r < 16; ++r){
                int trow = (r&3) + 8*(r>>2) + 4*half;
                float e = exp2f(accS[i][r]);
                if (ct == rt && l31 > trow) e = 0.0f;   // causal mask, diagonal tile
                accS[i][r] = e;
            }
        }
    }

    // partial rowsum over this wave's tiles (unowned accS == 0), butterfly per half
    float ps[16];
    #pragma unroll
    for (int r = 0; r < 16; ++r){
        float l = accS[0][r] + accS[1][r];
        #pragma unroll
        for (int m = 1; m <= 16; m <<= 1)
            l += __shfl_xor(l, m);
        ps[r] = l;
    }
    __syncthreads();     // all waves done reading q,k (P overlays them)

    // ---------------- phase 2b: P -> LDS, partial rowsums -> RS ----------------
    #pragma unroll
    for (int i = 0; i < 2; ++i){
        int ct = cg + 2*i;
        if (ct <= rt){
            char* bp = smem + P_OFF + (32*ct + l31) * 2;
            #pragma unroll
            for (int r = 0; r < 16; ++r){
                int t = 32*rt + (r&3) + 8*(r>>2) + 4*half;
                *(unsigned short*)(bp + t * (P_PITCH*2)) = f2bf(accS[i][r]);
            }
        }
    }
    if (l31 == 0){       // one lane per half writes 16 row-partials
        #pragma unroll
        for (int r = 0; r < 16; ++r){
            int row = (r&3) + 8*(r>>2) + 4*half;
            *(float*)(smem + RS_OFF + ((rt*2 + cg)*32 + row)*4) = ps[r];
        }
    }
    __syncthreads();

    // linv for cg1 (the storing waves): broadcast reads, conflict-free
    float linv[16];
    if (cg){
        #pragma unroll
        for (int r = 0; r < 16; ++r){
            int row = (r&3) + 8*(r>>2) + 4*half;
            float s0 = *(const float*)(smem + RS_OFF + ((rt*2 + 0)*32 + row)*4);
            float s1 = *(const float*)(smem + RS_OFF + ((rt*2 + 1)*32 + row)*4);
            linv[r] = 1.0f / (s0 + s1);
        }
    }

    // O partial = sum over owned ct of P_tile x V
    floatx16 accO0 = {}, accO1 = {};
    #pragma unroll
    for (int i = 0; i < 2; ++i){
        int ct = cg + 2*i;
        if (ct <= rt){
            #pragma unroll
            for (int kk = 0; kk < 2; ++kk){
                int ks = 2*ct + kk;
                short8 ap  = ld_b64x2(smem + P_OFF + (32*rt + l31)*(P_PITCH*2) + (ks*16 + koff)*2);
                short8 bv0 = ld_b64x2(smem + V_OFF + l31        *(V_PITCH*2) + (ks*16 + koff)*2);
                short8 bv1 = ld_b64x2(smem + V_OFF + (l31 + 32) *(V_PITCH*2) + (ks*16 + koff)*2);
                accO0 = MFMA(ap, bv0, accO0);
                accO1 = MFMA(ap, bv1, accO1);
            }
        }
    }
    __syncthreads();     // P dead; OX overlays it

    // cross-wave O reduction: cg0 writes partials, cg1 adds + normalizes + stores
    if (cg == 0){
        char* ox = smem + OX_OFF + rt * 8192;
        #pragma unroll
        for (int r = 0; r < 16; ++r){
            int row = (r&3) + 8*(r>>2) + 4*half;
            *(float*)(ox + row*256 + l31*4)       = accO0[r];
            *(float*)(ox + row*256 + 128 + l31*4) = accO1[r];
        }
    }
    __syncthreads();
    if (cg == 1){
        const char* ox = smem + OX_OFF + rt * 8192;
        float* ob = out + (size_t)b * (T_DIM * HS);
        #pragma unroll
        for (int r = 0; r < 16; ++r){
            int row = (r&3) + 8*(r>>2) + 4*half;
            int t = 32*rt + row;
            float o0 = *(const float*)(ox + row*256 + l31*4)       + accO0[r];
            float o1 = *(const float*)(ox + row*256 + 128 + l31*4) + accO1[r];
            ob[t*HS + l31]      = o0 * linv[r];
            ob[t*HS + l31 + 32] = o1 * linv[r];
        }
    }
}

extern "C" void kernel_launch(void* const* d_in, const int* in_sizes, int n_in,
                              void* d_out, int out_size, void* d_ws, size_t ws_size,
                              hipStream_t stream){
    const float* x  = (const float*)d_in[0];
    const float* Wq = (const float*)d_in[1];
    const float* Wk = (const float*)d_in[2];
    const float* Wv = (const float*)d_in[3];
    unsigned short* wt = (unsigned short*)d_ws;   // 48*1536*2 = 147456 B used

    prep_wt<<<288, 256, 0, stream>>>(Wq, Wk, Wv, wt);
    attn_kernel<<<1024, 512, 0, stream>>>(x, wt, (float*)d_out);
}